// Round 5
// baseline (4229.555 us; speedup 1.0000x reference)
//
#include <hip/hip_runtime.h>
#include <hip/hip_bf16.h>
#include <cstdint>

// ============================================================================
// Neural-ODE actor: y0=[x,0...]; 4 RK4(3/8) steps, f = 72->256->256->72 MLP.
// Fully fused: one block owns 96 samples for all 16 f-evals (zero HBM
// intermediates). Split-bf16 MFMA (hi+lo bf16 per fp32; C = Ah*Bh + Al*Bh
// + Ah*Bl) ~= fp32 accuracy (~1e-5 rel) at MFMA rate. Weights pre-packed
// once per launch into exact MFMA B-fragment order in d_ws -> B-frags
// stream L2->L1->VGPR as coalesced dwordx4 (wm-pair duplication caught by
// L1; unique L2 demand ~17 TB/s at the 619us MFMA floor).
// Activations in LDS as interleaved (hi|lo<<16) u32 pairs, XOR-swizzled
// (byte ^= (row&7)<<4) -> <=2-way bank aliasing (free, m136).
// Correctness notes: self-consistent kappa on the k-axis is exact for any
// bijection given A/B operand slot-map symmetry (A row=lane&15, B col=
// lane&15, identical (lane-group,reg)->k map — the property all shared-
// pattern GEMM fragment loaders rely on); C/D map is the m89-verified
// col=lane&15, row=(lane>>4)*4+reg. RK4 state algebra avoids k1/k2 storage:
// z2=y+dt/3*k1; z3=2y-z2+dt*k2; z4=2z2-z3+dt*k3;
// y' = y + (6z2+3z3-9y+3dt*k3+dt*k4)/8.
// Desk-audited r2/r3/r4: swizzle involution + in-bounds, bank<=2-way on all
// LDS ops, v_perm pool order vs ISA, barrier hazard graph, tail guards,
// output contract, graph-capture safety, kappa-symmetry derivation.
// ============================================================================

#define IN_DIM 15
#define CD     36
#define STATE  72
#define KP1    96      // K of GEMM1 padded to 3*32 (sZ width)
#define HID    256
#define NP3    128     // N of GEMM3 padded to 8*16
#define MT     96      // samples per block
#define NTHR   512

typedef short    bf16x8 __attribute__((ext_vector_type(8)));
typedef float    f32x4  __attribute__((ext_vector_type(4)));
typedef uint32_t u32;
typedef u32      u32x4  __attribute__((ext_vector_type(4)));

// ws layout, int4 (16B) units: frag index = (s*NT + t)*64 + lane
#define W1H 0
#define W1L 3072
#define W2H 6144
#define W2L 14336
#define W3H 22528
#define W3L 26624
// total 30720 int4 = 480 KB of d_ws

// split fp32 -> (bf16 hi | bf16 lo << 16), RNE both; hi+lo == v to ~2^-17 rel
__device__ __forceinline__ u32 pack_split(float v) {
    u32 u  = __builtin_bit_cast(u32, v);
    u32 h  = (u + 0x7FFFu + ((u >> 16) & 1u)) >> 16;
    float hf = __builtin_bit_cast(float, h << 16);
    float l  = v - hf;                       // exact 2-term split
    u32 lu = __builtin_bit_cast(u32, l);
    u32 lo = (lu + 0x7FFFu + ((lu >> 16) & 1u)) >> 16;
    return h | (lo << 16);
}
__device__ __forceinline__ float unpack_pair(u32 p) {
    return __builtin_bit_cast(float, p << 16) +
           __builtin_bit_cast(float, p & 0xFFFF0000u);
}

// ---------------------------------------------------------------------------
// Prep: pack W1/W2/W3 (hi,lo) into MFMA B-frag order, zero-padding K/N.
// k-map kappa(g,j): j<4 -> 32s + 4g + j ; j>=4 -> 32s + 16 + 4g + (j-4).
// Any bijection is exact as long as A-reads use the same one (they do).
// ---------------------------------------------------------------------------
__global__ void prep_pack(const float* __restrict__ W1, const float* __restrict__ W2,
                          const float* __restrict__ W3, int4* __restrict__ ws) {
    int tid = blockIdx.x * 256 + threadIdx.x;
    if (tid >= 15360) return;
    const float* W; int NT, Kr, Nr, lidx, oh, ol;
    if (tid < 3072)       { W = W1; NT = 16; Kr = 72;  Nr = 256; lidx = tid;         oh = W1H; ol = W1L; }
    else if (tid < 11264) { W = W2; NT = 16; Kr = 256; Nr = 256; lidx = tid - 3072;  oh = W2H; ol = W2L; }
    else                  { W = W3; NT = 8;  Kr = 256; Nr = 72;  lidx = tid - 11264; oh = W3H; ol = W3L; }
    int lane = lidx & 63;
    int t    = (lidx >> 6) % NT;
    int s    = (lidx >> 6) / NT;
    int g = lane >> 4, c = lane & 15;
    int nn = t * 16 + c;
    u32 hw[4], lw[4];
    #pragma unroll
    for (int p = 0; p < 4; ++p) {
        u32 hh = 0, ll = 0;
        #pragma unroll
        for (int q = 0; q < 2; ++q) {
            int j  = 2 * p + q;
            int kk = s * 32 + ((j < 4) ? (g * 4 + j) : (16 + g * 4 + (j - 4)));
            float w = 0.f;
            if (kk < Kr && nn < Nr) w = W[kk * Nr + nn];
            u32 pr = pack_split(w);
            hh |= (pr & 0xFFFFu) << (16 * q);
            ll |= (pr >> 16)     << (16 * q);
        }
        hw[p] = hh; lw[p] = ll;
    }
    u32x4 H = {hw[0], hw[1], hw[2], hw[3]};
    u32x4 L = {lw[0], lw[1], lw[2], lw[3]};
    ws[oh + lidx] = __builtin_bit_cast(int4, H);
    ws[ol + lidx] = __builtin_bit_cast(int4, L);
}

// ---------------------------------------------------------------------------
// A-fragment (hi,lo) from interleaved-pair LDS buffer.
// Lane reads its A row (lane&15); k-elems j0..3 at colbytes cb..cb+15,
// j4..7 at cb+64.. (matches kappa; cb = s*128 + (lane>>4)*16). XOR swizzle
// (row&7)<<4 applied to the full byte column offset, matching the writers.
// v_perm splits each (hi|lo<<16) u32 pair into hi-plane / lo-plane bf16x8.
// ---------------------------------------------------------------------------
__device__ __forceinline__ void load_afrag(const u32* Abuf, int rowb_u32, int row,
                                           int cb, bf16x8& ah, bf16x8& al) {
    const char* base = (const char*)(Abuf + row * rowb_u32);
    int sw = (row & 7) << 4;
    int4 v03 = *(const int4*)(base + (cb ^ sw));
    int4 v47 = *(const int4*)(base + ((cb + 64) ^ sw));
    u32 h0 = __builtin_amdgcn_perm((u32)v03.y, (u32)v03.x, 0x05040100u);
    u32 l0 = __builtin_amdgcn_perm((u32)v03.y, (u32)v03.x, 0x07060302u);
    u32 h1 = __builtin_amdgcn_perm((u32)v03.w, (u32)v03.z, 0x05040100u);
    u32 l1 = __builtin_amdgcn_perm((u32)v03.w, (u32)v03.z, 0x07060302u);
    u32 h2 = __builtin_amdgcn_perm((u32)v47.y, (u32)v47.x, 0x05040100u);
    u32 l2 = __builtin_amdgcn_perm((u32)v47.y, (u32)v47.x, 0x07060302u);
    u32 h3 = __builtin_amdgcn_perm((u32)v47.w, (u32)v47.z, 0x05040100u);
    u32 l3 = __builtin_amdgcn_perm((u32)v47.w, (u32)v47.z, 0x07060302u);
    u32x4 hv = {h0, h1, h2, h3}, lv = {l0, l1, l2, l3};
    ah = __builtin_bit_cast(bf16x8, hv);
    al = __builtin_bit_cast(bf16x8, lv);
}

// One layer GEMM: A = [96 x 32*NS] pairs in LDS, B = frag-packed global.
// Wave (wm,wn): m-tiles {wm*48 + mm*16}, n-tiles {wn*TT + tt}.
// 3 MFMAs per (mm,tt,s): Ah*Bh + Al*Bh + Ah*Bl (split-bf16).
template<int NS, int NT, int TT, int ROWB>
__device__ __forceinline__ void gemm_layer(const u32* Abuf, const int4* ph, const int4* pl,
                                           const float* bias, int wm, int wn, int lane,
                                           f32x4 (&acc)[3][TT]) {
    const int lc = lane & 15, lr = lane >> 4;
    #pragma unroll
    for (int mm = 0; mm < 3; ++mm)
        #pragma unroll
        for (int tt = 0; tt < TT; ++tt) {
            float bv = bias[(wn * TT + tt) * 16 + lc];
            acc[mm][tt] = (f32x4){bv, bv, bv, bv};
        }
    #pragma unroll 2
    for (int s = 0; s < NS; ++s) {
        int4 bh[TT], bl[TT];
        #pragma unroll
        for (int tt = 0; tt < TT; ++tt) {
            int fi = (s * NT + wn * TT + tt) * 64 + lane;
            bh[tt] = ph[fi]; bl[tt] = pl[fi];
        }
        bf16x8 ah[3], al[3];
        #pragma unroll
        for (int mm = 0; mm < 3; ++mm)
            load_afrag(Abuf, ROWB / 4, wm * 48 + mm * 16 + lc, s * 128 + lr * 16, ah[mm], al[mm]);
        #pragma unroll
        for (int mm = 0; mm < 3; ++mm)
            #pragma unroll
            for (int tt = 0; tt < TT; ++tt) {
                bf16x8 bhv = __builtin_bit_cast(bf16x8, bh[tt]);
                bf16x8 blv = __builtin_bit_cast(bf16x8, bl[tt]);
                acc[mm][tt] = __builtin_amdgcn_mfma_f32_16x16x32_bf16(ah[mm], bhv, acc[mm][tt], 0, 0, 0);
                acc[mm][tt] = __builtin_amdgcn_mfma_f32_16x16x32_bf16(al[mm], bhv, acc[mm][tt], 0, 0, 0);
                acc[mm][tt] = __builtin_amdgcn_mfma_f32_16x16x32_bf16(ah[mm], blv, acc[mm][tt], 0, 0, 0);
            }
    }
}

// ---------------------------------------------------------------------------
// Fused ODE kernel. 512 thr (8 waves, 2x4 wave grid), 96 samples/block.
// LDS 134.5 KB -> 1 block/CU, 2 waves/SIMD (MFMA/VALU co-schedule, m114).
// ---------------------------------------------------------------------------
__global__ __launch_bounds__(NTHR, 2) void ode_fused(
    const float* __restrict__ x, const float* __restrict__ b1,
    const float* __restrict__ b2, const float* __restrict__ b3,
    const int4* __restrict__ ws, float* __restrict__ out, int Bn) {

    __shared__ u32 sH[MT * HID];   // 96 KB: h1/h2 (hi|lo pairs, swizzled)
    __shared__ u32 sZ[MT * KP1];   // 36 KB: z (cols 72..95 stay 0)
    __shared__ float sB1[HID], sB2[HID], sB3[NP3];

    const int tid  = threadIdx.x;
    const int lane = tid & 63, wv = tid >> 6;
    const int wm = wv >> 2, wn = wv & 3;
    const int lr = lane >> 4, lc = lane & 15;
    const int m0 = blockIdx.x * MT;

    for (int i = tid; i < HID; i += NTHR) { sB1[i] = b1[i]; sB2[i] = b2[i]; }
    for (int i = tid; i < NP3; i += NTHR) {
        float v = 0.f;
        if (i < STATE) v = b3[i];
        sB3[i] = v;
    }

    // --- init: Y = y0 = [x, 0...]; sZ = split(Y). Ownership == G3 C-map.
    float Y[3][2][4];
    #pragma unroll
    for (int mm = 0; mm < 3; ++mm)
        #pragma unroll
        for (int tt = 0; tt < 2; ++tt) {
            int d = (wn * 2 + tt) * 16 + lc;
            #pragma unroll
            for (int r = 0; r < 4; ++r) {
                int row = wm * 48 + mm * 16 + lr * 4 + r;
                int m   = m0 + row;
                float v = 0.f;
                if (d < IN_DIM && m < Bn) v = x[m * IN_DIM + d];
                Y[mm][tt][r] = v;
                if (d < KP1) sZ[row * KP1 + (d ^ ((row & 7) << 2))] = pack_split(v);
            }
        }
    __syncthreads();

    float Z2[3][2][4], Pa[3][2][4];

    #pragma unroll 1
    for (int step = 0; step < 4; ++step) {
        float dt = (step == 3) ? 0.1f : 0.3f;
        #pragma unroll 1
        for (int j = 0; j < 4; ++j) {
            // ---- GEMM1: h1 = relu(z @ W1 + b1), K=96(pad), N=256
            f32x4 acc[3][4];
            gemm_layer<3, 16, 4, KP1 * 4>(sZ, ws + W1H, ws + W1L, sB1, wm, wn, lane, acc);
            #pragma unroll
            for (int mm = 0; mm < 3; ++mm)
                #pragma unroll
                for (int tt = 0; tt < 4; ++tt)
                    #pragma unroll
                    for (int r = 0; r < 4; ++r) {
                        int row = wm * 48 + mm * 16 + lr * 4 + r;
                        int col = (wn * 4 + tt) * 16 + lc;
                        float v = fmaxf(acc[mm][tt][r], 0.f);
                        sH[row * HID + (col ^ ((row & 7) << 2))] = pack_split(v);
                    }
            __syncthreads();

            // ---- GEMM2: h2 = relu(h1 @ W2 + b2), K=256, N=256
            gemm_layer<8, 16, 4, HID * 4>(sH, ws + W2H, ws + W2L, sB2, wm, wn, lane, acc);
            __syncthreads();                      // all h1 reads done
            #pragma unroll
            for (int mm = 0; mm < 3; ++mm)
                #pragma unroll
                for (int tt = 0; tt < 4; ++tt)
                    #pragma unroll
                    for (int r = 0; r < 4; ++r) {
                        int row = wm * 48 + mm * 16 + lr * 4 + r;
                        int col = (wn * 4 + tt) * 16 + lc;
                        float v = fmaxf(acc[mm][tt][r], 0.f);
                        sH[row * HID + (col ^ ((row & 7) << 2))] = pack_split(v);
                    }
            __syncthreads();

            // ---- GEMM3: k = h2 @ W3 + b3, K=256, N=128(pad; cols>=72 all 0)
            f32x4 acc3[3][2];
            gemm_layer<8, 8, 2, HID * 4>(sH, ws + W3H, ws + W3L, sB3, wm, wn, lane, acc3);

            // ---- RK4 owner update (each thread owns its C elements)
            #pragma unroll
            for (int mm = 0; mm < 3; ++mm)
                #pragma unroll
                for (int tt = 0; tt < 2; ++tt) {
                    int d = (wn * 2 + tt) * 16 + lc;
                    #pragma unroll
                    for (int r = 0; r < 4; ++r) {
                        int row = wm * 48 + mm * 16 + lr * 4 + r;
                        int zi  = row * KP1 + (d ^ ((row & 7) << 2));
                        float C = acc3[mm][tt][r];
                        float y = Y[mm][tt][r];
                        if (j == 0) {
                            float z = y + (dt * (1.f / 3.f)) * C;
                            if (d < KP1) sZ[zi] = pack_split(z);
                        } else if (j == 1) {
                            float z2 = 0.f;
                            if (d < KP1) z2 = unpack_pair(sZ[zi]);
                            Z2[mm][tt][r] = z2;
                            float z = 2.f * y - z2 + dt * C;
                            if (d < KP1) sZ[zi] = pack_split(z);
                        } else if (j == 2) {
                            float z3 = 0.f;
                            if (d < KP1) z3 = unpack_pair(sZ[zi]);
                            float z2 = Z2[mm][tt][r];
                            float z = 2.f * z2 - z3 + dt * C;
                            if (d < KP1) sZ[zi] = pack_split(z);
                            Pa[mm][tt][r] = 6.f * z2 + 3.f * z3 - 9.f * y + 3.f * dt * C;
                        } else {
                            float yn = y + (Pa[mm][tt][r] + dt * C) * 0.125f;
                            Y[mm][tt][r] = yn;
                            if (step < 3 && d < KP1) sZ[zi] = pack_split(yn);
                        }
                    }
                }
            __syncthreads();
        }
    }

    // ---- outputs: action = clip(y[15:27],±1), force = clip(y[27:36],±2)
    #pragma unroll
    for (int mm = 0; mm < 3; ++mm)
        #pragma unroll
        for (int tt = 0; tt < 2; ++tt) {
            int d = (wn * 2 + tt) * 16 + lc;
            #pragma unroll
            for (int r = 0; r < 4; ++r) {
                int m = m0 + wm * 48 + mm * 16 + lr * 4 + r;
                if (m >= Bn) continue;
                float v = Y[mm][tt][r];
                if (d >= IN_DIM && d < IN_DIM + 12)
                    out[m * 12 + (d - IN_DIM)] = fminf(fmaxf(v, -1.f), 1.f);
                else if (d >= IN_DIM + 12 && d < CD)
                    out[Bn * 12 + m * 9 + (d - IN_DIM - 12)] = fminf(fmaxf(v, -2.f), 2.f);
            }
        }
}

extern "C" void kernel_launch(void* const* d_in, const int* in_sizes, int n_in,
                              void* d_out, int out_size, void* d_ws, size_t ws_size,
                              hipStream_t stream) {
    const float* x  = (const float*)d_in[0];
    const float* W1 = (const float*)d_in[1];
    const float* b1 = (const float*)d_in[2];
    const float* W2 = (const float*)d_in[3];
    const float* b2 = (const float*)d_in[4];
    const float* W3 = (const float*)d_in[5];
    const float* b3 = (const float*)d_in[6];
    int Bn = in_sizes[0] / IN_DIM;
    int4* ws = (int4*)d_ws;   // needs 480 KB

    hipLaunchKernelGGL(prep_pack, dim3(60), dim3(256), 0, stream, W1, W2, W3, ws);
    int grid = (Bn + MT - 1) / MT;
    hipLaunchKernelGGL(ode_fused, dim3(grid), dim3(NTHR), 0, stream,
                       x, b1, b2, b3, ws, (float*)d_out, Bn);
}

// Round 7
// 3634.345 us; speedup vs baseline: 1.1638x; 1.1638x over previous
//
#include <hip/hip_runtime.h>
#include <hip/hip_bf16.h>
#include <cstdint>

// ============================================================================
// Neural-ODE actor: y0=[x,0...]; 4 RK4(3/8) steps, f = 72->256->256->72 MLP.
// Fully fused: one block owns 96 samples for all 16 f-evals. Split-bf16 MFMA
// (hi+lo bf16 per fp32; C = Ah*Bh + Al*Bh + Ah*Bl) ~ fp32 accuracy at MFMA
// rate. Weights pre-packed into MFMA B-frag order in d_ws (L2-resident).
// Activations in LDS as (hi|lo<<16) u32 pairs, XOR-swizzled.
//
// R5 post-mortem: compiler chose 128 VGPRs (targeting 4 waves/EU) although
// LDS 134.5KB caps occupancy at 1 block/CU (2 waves/SIMD) -> ~230 live regs
// spilled to scratch: WRITE_SIZE 1.35GB (vs 11MB legit), FETCH_SIZE 3.4GB
// (spill reloads + scratch thrashing L2 evicting the 480KB weight set).
// dur 4.37ms, MfmaUtil 15%. Fix: amdgpu_waves_per_eu(2,2) pins the budget
// to 256 VGPR, and Z2/Pa merged into one St array (-24 regs persistent).
// ============================================================================

#define IN_DIM 15
#define CD     36
#define STATE  72
#define KP1    96      // K of GEMM1 padded to 3*32 (sZ width)
#define HID    256
#define NP3    128     // N of GEMM3 padded to 8*16
#define MT     96      // samples per block
#define NTHR   512

typedef short    bf16x8 __attribute__((ext_vector_type(8)));
typedef float    f32x4  __attribute__((ext_vector_type(4)));
typedef uint32_t u32;
typedef u32      u32x4  __attribute__((ext_vector_type(4)));

// ws layout, int4 (16B) units: frag index = (s*NT + t)*64 + lane
#define W1H 0
#define W1L 3072
#define W2H 6144
#define W2L 14336
#define W3H 22528
#define W3L 26624
// total 30720 int4 = 480 KB of d_ws

// split fp32 -> (bf16 hi | bf16 lo << 16), RNE both; hi+lo == v to ~2^-17 rel
__device__ __forceinline__ u32 pack_split(float v) {
    u32 u  = __builtin_bit_cast(u32, v);
    u32 h  = (u + 0x7FFFu + ((u >> 16) & 1u)) >> 16;
    float hf = __builtin_bit_cast(float, h << 16);
    float l  = v - hf;                       // exact 2-term split
    u32 lu = __builtin_bit_cast(u32, l);
    u32 lo = (lu + 0x7FFFu + ((lu >> 16) & 1u)) >> 16;
    return h | (lo << 16);
}
__device__ __forceinline__ float unpack_pair(u32 p) {
    return __builtin_bit_cast(float, p << 16) +
           __builtin_bit_cast(float, p & 0xFFFF0000u);
}

// ---------------------------------------------------------------------------
// Prep: pack W1/W2/W3 (hi,lo) into MFMA B-frag order, zero-padding K/N.
// k-map kappa(g,j): j<4 -> 32s + 4g + j ; j>=4 -> 32s + 16 + 4g + (j-4).
// Any bijection is exact as long as A-reads use the same one (they do).
// ---------------------------------------------------------------------------
__global__ void prep_pack(const float* __restrict__ W1, const float* __restrict__ W2,
                          const float* __restrict__ W3, int4* __restrict__ ws) {
    int tid = blockIdx.x * 256 + threadIdx.x;
    if (tid >= 15360) return;
    const float* W; int NT, Kr, Nr, lidx, oh, ol;
    if (tid < 3072)       { W = W1; NT = 16; Kr = 72;  Nr = 256; lidx = tid;         oh = W1H; ol = W1L; }
    else if (tid < 11264) { W = W2; NT = 16; Kr = 256; Nr = 256; lidx = tid - 3072;  oh = W2H; ol = W2L; }
    else                  { W = W3; NT = 8;  Kr = 256; Nr = 72;  lidx = tid - 11264; oh = W3H; ol = W3L; }
    int lane = lidx & 63;
    int t    = (lidx >> 6) % NT;
    int s    = (lidx >> 6) / NT;
    int g = lane >> 4, c = lane & 15;
    int nn = t * 16 + c;
    u32 hw[4], lw[4];
    #pragma unroll
    for (int p = 0; p < 4; ++p) {
        u32 hh = 0, ll = 0;
        #pragma unroll
        for (int q = 0; q < 2; ++q) {
            int j  = 2 * p + q;
            int kk = s * 32 + ((j < 4) ? (g * 4 + j) : (16 + g * 4 + (j - 4)));
            float w = 0.f;
            if (kk < Kr && nn < Nr) w = W[kk * Nr + nn];
            u32 pr = pack_split(w);
            hh |= (pr & 0xFFFFu) << (16 * q);
            ll |= (pr >> 16)     << (16 * q);
        }
        hw[p] = hh; lw[p] = ll;
    }
    u32x4 H = {hw[0], hw[1], hw[2], hw[3]};
    u32x4 L = {lw[0], lw[1], lw[2], lw[3]};
    ws[oh + lidx] = __builtin_bit_cast(int4, H);
    ws[ol + lidx] = __builtin_bit_cast(int4, L);
}

// ---------------------------------------------------------------------------
// A-fragment (hi,lo) from interleaved-pair LDS buffer.
// Lane reads its A row (lane&15); k-elems j0..3 at colbytes cb..cb+15,
// j4..7 at cb+64.. (matches kappa; cb = s*128 + (lane>>4)*16). XOR swizzle
// (row&7)<<4 applied to the full byte column offset, matching the writers.
// v_perm splits each (hi|lo<<16) u32 pair into hi-plane / lo-plane bf16x8.
// ---------------------------------------------------------------------------
__device__ __forceinline__ void load_afrag(const u32* Abuf, int rowb_u32, int row,
                                           int cb, bf16x8& ah, bf16x8& al) {
    const char* base = (const char*)(Abuf + row * rowb_u32);
    int sw = (row & 7) << 4;
    int4 v03 = *(const int4*)(base + (cb ^ sw));
    int4 v47 = *(const int4*)(base + ((cb + 64) ^ sw));
    u32 h0 = __builtin_amdgcn_perm((u32)v03.y, (u32)v03.x, 0x05040100u);
    u32 l0 = __builtin_amdgcn_perm((u32)v03.y, (u32)v03.x, 0x07060302u);
    u32 h1 = __builtin_amdgcn_perm((u32)v03.w, (u32)v03.z, 0x05040100u);
    u32 l1 = __builtin_amdgcn_perm((u32)v03.w, (u32)v03.z, 0x07060302u);
    u32 h2 = __builtin_amdgcn_perm((u32)v47.y, (u32)v47.x, 0x05040100u);
    u32 l2 = __builtin_amdgcn_perm((u32)v47.y, (u32)v47.x, 0x07060302u);
    u32 h3 = __builtin_amdgcn_perm((u32)v47.w, (u32)v47.z, 0x05040100u);
    u32 l3 = __builtin_amdgcn_perm((u32)v47.w, (u32)v47.z, 0x07060302u);
    u32x4 hv = {h0, h1, h2, h3}, lv = {l0, l1, l2, l3};
    ah = __builtin_bit_cast(bf16x8, hv);
    al = __builtin_bit_cast(bf16x8, lv);
}

// One layer GEMM: A = [96 x 32*NS] pairs in LDS, B = frag-packed global.
// Wave (wm,wn): m-tiles {wm*48 + mm*16}, n-tiles {wn*TT + tt}.
// 3 MFMAs per (mm,tt,s): Ah*Bh + Al*Bh + Ah*Bl (split-bf16).
template<int NS, int NT, int TT, int ROWB>
__device__ __forceinline__ void gemm_layer(const u32* Abuf, const int4* ph, const int4* pl,
                                           const float* bias, int wm, int wn, int lane,
                                           f32x4 (&acc)[3][TT]) {
    const int lc = lane & 15, lr = lane >> 4;
    #pragma unroll
    for (int mm = 0; mm < 3; ++mm)
        #pragma unroll
        for (int tt = 0; tt < TT; ++tt) {
            float bv = bias[(wn * TT + tt) * 16 + lc];
            acc[mm][tt] = (f32x4){bv, bv, bv, bv};
        }
    #pragma unroll 2
    for (int s = 0; s < NS; ++s) {
        int4 bh[TT], bl[TT];
        #pragma unroll
        for (int tt = 0; tt < TT; ++tt) {
            int fi = (s * NT + wn * TT + tt) * 64 + lane;
            bh[tt] = ph[fi]; bl[tt] = pl[fi];
        }
        bf16x8 ah[3], al[3];
        #pragma unroll
        for (int mm = 0; mm < 3; ++mm)
            load_afrag(Abuf, ROWB / 4, wm * 48 + mm * 16 + lc, s * 128 + lr * 16, ah[mm], al[mm]);
        #pragma unroll
        for (int mm = 0; mm < 3; ++mm)
            #pragma unroll
            for (int tt = 0; tt < TT; ++tt) {
                bf16x8 bhv = __builtin_bit_cast(bf16x8, bh[tt]);
                bf16x8 blv = __builtin_bit_cast(bf16x8, bl[tt]);
                acc[mm][tt] = __builtin_amdgcn_mfma_f32_16x16x32_bf16(ah[mm], bhv, acc[mm][tt], 0, 0, 0);
                acc[mm][tt] = __builtin_amdgcn_mfma_f32_16x16x32_bf16(al[mm], bhv, acc[mm][tt], 0, 0, 0);
                acc[mm][tt] = __builtin_amdgcn_mfma_f32_16x16x32_bf16(ah[mm], blv, acc[mm][tt], 0, 0, 0);
            }
    }
}

// ---------------------------------------------------------------------------
// Fused ODE kernel. 512 thr (8 waves, 2x4 wave grid), 96 samples/block.
// LDS 134.5 KB -> 1 block/CU, 2 waves/SIMD. waves_per_eu(2,2) pins the
// register budget to 256 VGPR (occupancy is LDS-capped anyway) -> no spill.
// ---------------------------------------------------------------------------
__attribute__((amdgpu_waves_per_eu(2, 2)))
__global__ __launch_bounds__(NTHR, 2) void ode_fused(
    const float* __restrict__ x, const float* __restrict__ b1,
    const float* __restrict__ b2, const float* __restrict__ b3,
    const int4* __restrict__ ws, float* __restrict__ out, int Bn) {

    __shared__ u32 sH[MT * HID];   // 96 KB: h1/h2 (hi|lo pairs, swizzled)
    __shared__ u32 sZ[MT * KP1];   // 36 KB: z (cols 72..95 stay 0)
    __shared__ float sB1[HID], sB2[HID], sB3[NP3];

    const int tid  = threadIdx.x;
    const int lane = tid & 63, wv = tid >> 6;
    const int wm = wv >> 2, wn = wv & 3;
    const int lr = lane >> 4, lc = lane & 15;
    const int m0 = blockIdx.x * MT;

    for (int i = tid; i < HID; i += NTHR) { sB1[i] = b1[i]; sB2[i] = b2[i]; }
    for (int i = tid; i < NP3; i += NTHR) {
        float v = 0.f;
        if (i < STATE) v = b3[i];
        sB3[i] = v;
    }

    // --- init: Y = y0 = [x, 0...]; sZ = split(Y). Ownership == G3 C-map.
    float Y[3][2][4];
    #pragma unroll
    for (int mm = 0; mm < 3; ++mm)
        #pragma unroll
        for (int tt = 0; tt < 2; ++tt) {
            int d = (wn * 2 + tt) * 16 + lc;
            #pragma unroll
            for (int r = 0; r < 4; ++r) {
                int row = wm * 48 + mm * 16 + lr * 4 + r;
                int m   = m0 + row;
                float v = 0.f;
                if (d < IN_DIM && m < Bn) v = x[m * IN_DIM + d];
                Y[mm][tt][r] = v;
                if (d < KP1) sZ[row * KP1 + (d ^ ((row & 7) << 2))] = pack_split(v);
            }
        }
    __syncthreads();

    // St: z2 while live (j=1->j=2), then the RK4 partial Pa (j=2->j=3).
    float St[3][2][4];

    #pragma unroll 1
    for (int step = 0; step < 4; ++step) {
        float dt = (step == 3) ? 0.1f : 0.3f;
        #pragma unroll 1
        for (int j = 0; j < 4; ++j) {
            // ---- GEMM1: h1 = relu(z @ W1 + b1), K=96(pad), N=256
            f32x4 acc[3][4];
            gemm_layer<3, 16, 4, KP1 * 4>(sZ, ws + W1H, ws + W1L, sB1, wm, wn, lane, acc);
            #pragma unroll
            for (int mm = 0; mm < 3; ++mm)
                #pragma unroll
                for (int tt = 0; tt < 4; ++tt)
                    #pragma unroll
                    for (int r = 0; r < 4; ++r) {
                        int row = wm * 48 + mm * 16 + lr * 4 + r;
                        int col = (wn * 4 + tt) * 16 + lc;
                        float v = fmaxf(acc[mm][tt][r], 0.f);
                        sH[row * HID + (col ^ ((row & 7) << 2))] = pack_split(v);
                    }
            __syncthreads();

            // ---- GEMM2: h2 = relu(h1 @ W2 + b2), K=256, N=256
            gemm_layer<8, 16, 4, HID * 4>(sH, ws + W2H, ws + W2L, sB2, wm, wn, lane, acc);
            __syncthreads();                      // all h1 reads done
            #pragma unroll
            for (int mm = 0; mm < 3; ++mm)
                #pragma unroll
                for (int tt = 0; tt < 4; ++tt)
                    #pragma unroll
                    for (int r = 0; r < 4; ++r) {
                        int row = wm * 48 + mm * 16 + lr * 4 + r;
                        int col = (wn * 4 + tt) * 16 + lc;
                        float v = fmaxf(acc[mm][tt][r], 0.f);
                        sH[row * HID + (col ^ ((row & 7) << 2))] = pack_split(v);
                    }
            __syncthreads();

            // ---- GEMM3: k = h2 @ W3 + b3, K=256, N=128(pad; cols>=72 all 0)
            f32x4 acc3[3][2];
            gemm_layer<8, 8, 2, HID * 4>(sH, ws + W3H, ws + W3L, sB3, wm, wn, lane, acc3);

            // ---- RK4 owner update (each thread owns its C elements)
            #pragma unroll
            for (int mm = 0; mm < 3; ++mm)
                #pragma unroll
                for (int tt = 0; tt < 2; ++tt) {
                    int d = (wn * 2 + tt) * 16 + lc;
                    #pragma unroll
                    for (int r = 0; r < 4; ++r) {
                        int row = wm * 48 + mm * 16 + lr * 4 + r;
                        int zi  = row * KP1 + (d ^ ((row & 7) << 2));
                        float C = acc3[mm][tt][r];
                        float y = Y[mm][tt][r];
                        if (j == 0) {
                            float z = y + (dt * (1.f / 3.f)) * C;
                            if (d < KP1) sZ[zi] = pack_split(z);
                        } else if (j == 1) {
                            float z2 = 0.f;
                            if (d < KP1) z2 = unpack_pair(sZ[zi]);
                            St[mm][tt][r] = z2;
                            float z = 2.f * y - z2 + dt * C;
                            if (d < KP1) sZ[zi] = pack_split(z);
                        } else if (j == 2) {
                            float z3 = 0.f;
                            if (d < KP1) z3 = unpack_pair(sZ[zi]);
                            float z2 = St[mm][tt][r];
                            float z = 2.f * z2 - z3 + dt * C;
                            if (d < KP1) sZ[zi] = pack_split(z);
                            St[mm][tt][r] = 6.f * z2 + 3.f * z3 - 9.f * y + 3.f * dt * C;
                        } else {
                            float yn = y + (St[mm][tt][r] + dt * C) * 0.125f;
                            Y[mm][tt][r] = yn;
                            if (step < 3 && d < KP1) sZ[zi] = pack_split(yn);
                        }
                    }
                }
            __syncthreads();
        }
    }

    // ---- outputs: action = clip(y[15:27],±1), force = clip(y[27:36],±2)
    #pragma unroll
    for (int mm = 0; mm < 3; ++mm)
        #pragma unroll
        for (int tt = 0; tt < 2; ++tt) {
            int d = (wn * 2 + tt) * 16 + lc;
            #pragma unroll
            for (int r = 0; r < 4; ++r) {
                int m = m0 + wm * 48 + mm * 16 + lr * 4 + r;
                if (m >= Bn) continue;
                float v = Y[mm][tt][r];
                if (d >= IN_DIM && d < IN_DIM + 12)
                    out[m * 12 + (d - IN_DIM)] = fminf(fmaxf(v, -1.f), 1.f);
                else if (d >= IN_DIM + 12 && d < CD)
                    out[Bn * 12 + m * 9 + (d - IN_DIM - 12)] = fminf(fmaxf(v, -2.f), 2.f);
            }
        }
}

extern "C" void kernel_launch(void* const* d_in, const int* in_sizes, int n_in,
                              void* d_out, int out_size, void* d_ws, size_t ws_size,
                              hipStream_t stream) {
    const float* x  = (const float*)d_in[0];
    const float* W1 = (const float*)d_in[1];
    const float* b1 = (const float*)d_in[2];
    const float* W2 = (const float*)d_in[3];
    const float* b2 = (const float*)d_in[4];
    const float* W3 = (const float*)d_in[5];
    const float* b3 = (const float*)d_in[6];
    int Bn = in_sizes[0] / IN_DIM;
    int4* ws = (int4*)d_ws;   // needs 480 KB

    hipLaunchKernelGGL(prep_pack, dim3(60), dim3(256), 0, stream, W1, W2, W3, ws);
    int grid = (Bn + MT - 1) / MT;
    hipLaunchKernelGGL(ode_fused, dim3(grid), dim3(NTHR), 0, stream,
                       x, b1, b2, b3, ws, (float*)d_out, Bn);
}